// Round 14
// baseline (312.247 us; speedup 1.0000x reference)
//
#include <hip/hip_runtime.h>
#include <hip/hip_bf16.h>

// ---------------------------------------------------------------------------
// TileSelfAttention, round 14.
// QKV GEMM: dual-digit i8, 256x256, counted-vmcnt (R13-proven), restructured:
//   3 phases/chunk (3 barriers, 0 manual lgkm), mfma_i32_32x32x32_i8
//   (+12% rate, half the instructions).  Wave tile 128x64 = 4x2 tiles of 32².
//   Fragment-order LDS (0 conflicts): A[mt][ks][lane*16], B[nt][ks][lane*16],
//   lane -> (row=l&31, k16=l>>5).  Shift-fold high pass: acc += mfma(qh,ph)<<7.
// ---------------------------------------------------------------------------

typedef __bf16 bf16;
using i32x4  = __attribute__((ext_vector_type(4))) int;
using i32x16 = __attribute__((ext_vector_type(16))) int;

#define NT     64
#define BATCH  512

#define OFF_XQH 0ul
#define OFF_XQL 33554432ul
#define OFF_WT  67108864ul
#define OFF_K   70254592ul
#define OFF_Q   137363456ul
#define OFF_V   204472320ul
#define OFF_AW  271581184ul
#define OFF_MS  279969792ul

// ---------------------------------------------------------------------------
__global__ void quant_kernel(const float* __restrict__ x,
                             unsigned int* __restrict__ qh,
                             unsigned int* __restrict__ ql, int n4, float invS) {
  int i = blockIdx.x * blockDim.x + threadIdx.x;
  int stride = gridDim.x * blockDim.x;
  for (; i < n4; i += stride) {
    float4 v = ((const float4*)x)[i];
    unsigned hw = 0, lw = 0;
#pragma unroll
    for (int j = 0; j < 4; ++j) {
      float f = (j == 0) ? v.x : (j == 1) ? v.y : (j == 2) ? v.z : v.w;
      int q = __float2int_rn(f * invS);
      q = max(-16320, min(16319, q));
      int h = (q + 64) >> 7;
      int lo = q - (h << 7);
      hw |= ((unsigned)(h & 0xFF)) << (8 * j);
      lw |= ((unsigned)(lo & 0xFF)) << (8 * j);
    }
    qh[i] = hw;
    ql[i] = lw;
  }
}

// ---------------------------------------------------------------------------
// quantize W into 32x32-fragment-tiled layout:
//   WT[proj] offset = ((ct32*16 + kc)*2 + ks)*2048 + plane*1024 + lane*16 + ki
//   ct32 = c>>5, kc = k>>6, ks = (k>>5)&1, lane = (c&31) | (((k>>4)&1)<<5),
//   ki = k&15.  plane 0 = ph, 1 = pl.
// ---------------------------------------------------------------------------
__global__ void quant_w_kernel(const float* __restrict__ W0,
                               const float* __restrict__ W1,
                               const float* __restrict__ W2,
                               char* __restrict__ WT, float invS) {
  int gid = blockIdx.x * blockDim.x + threadIdx.x;  // 0..393215
  int proj = gid >> 17;
  int idx = gid & 131071;
  const float* W = (proj == 0) ? W0 : (proj == 1 ? W1 : W2);
  int c = idx >> 8, k = (idx & 255) * 4;
  float4 v = ((const float4*)W)[idx];
  unsigned hw = 0, lw = 0;
#pragma unroll
  for (int j = 0; j < 4; ++j) {
    float f = (j == 0) ? v.x : (j == 1) ? v.y : (j == 2) ? v.z : v.w;
    int q = __float2int_rn(f * invS);
    q = max(-16320, min(16319, q));
    int h = (q + 64) >> 7;
    int lo = q - (h << 7);
    hw |= ((unsigned)(h & 0xFF)) << (8 * j);
    lw |= ((unsigned)(lo & 0xFF)) << (8 * j);
  }
  int ct32 = c >> 5;
  int kc = k >> 6, ks = (k >> 5) & 1;
  int lane = (c & 31) | (((k >> 4) & 1) << 5);
  int ki = k & 15;
  size_t dst = (size_t)proj * 1048576 +
               ((size_t)(ct32 * 16 + kc) * 2 + ks) * 2048 + lane * 16 + ki;
  *(unsigned int*)(WT + dst) = hw;          // ph plane
  *(unsigned int*)(WT + dst + 1024) = lw;   // pl plane
}

// ---------------------------------------------------------------------------
__device__ __forceinline__ void gl16(const char* g, char* l) {
  __builtin_amdgcn_global_load_lds(
      (const __attribute__((address_space(1))) unsigned int*)g,
      (__attribute__((address_space(3))) unsigned int*)l, 16, 0, 0);
}

#define VMC(n)  asm volatile("s_waitcnt vmcnt(" #n ")" ::: "memory")
#define BAR     __builtin_amdgcn_s_barrier()
#define SGB     __builtin_amdgcn_sched_barrier(0)
#define MFMA32  __builtin_amdgcn_mfma_i32_32x32x32_i8

__global__ __launch_bounds__(512, 2) void gemm_i8(
    const char* __restrict__ XQH, const char* __restrict__ XQL,
    const char* __restrict__ WT,
    const float* __restrict__ bk, const float* __restrict__ bq,
    const float* __restrict__ bv,
    float* __restrict__ K, float* __restrict__ Q, float* __restrict__ V) {
  __shared__ __align__(16) char lds[131072];  // 2 x 64KB
  // buffer: Aqh [0,16K) Aql [16K,32K) Bph [32K,48K) Bpl [48K,64K)
  // plane layout: [tile 0..7][ks 0..1][lane*16]

  // T1: bijective XCD swizzle (768 = 8 * 96); mt-major for A-panel L2 reuse
  const int bid = (blockIdx.x & 7) * 96 + (blockIdx.x >> 3);
  const int mtb = bid / 6, nb = bid % 6;
  const int gm0 = mtb * 256;
  const int proj = nb >> 1;
  const int nbl = nb & 1;
  const int wn0 = nbl * 256;

  const int tid = threadIdx.x;
  const int l = tid & 63, w = tid >> 6;
  const int wr = w >> 2, wc = w & 3;   // 8 waves: 2M x 4N, wave tile 128x64

  // A staging: unit u = tid (+512): mt=u>>7, ks=(u>>6)&1, lane=u&63
  const int arow = gm0 + ((tid >> 7) << 5) + (tid & 31);
  const int ak = (((tid >> 6) & 1) << 5) | (((tid >> 5) & 1) << 4);
  const char* aqh0 = XQH + (size_t)arow * 1024 + ak;
  const char* aql0 = XQL + (size_t)arow * 1024 + ak;
  // B staging from pre-tiled WT
  const char* wb0 = WT + (size_t)proj * 1048576 +
                    (size_t)(nbl * 8 + (tid >> 7)) * 65536 +
                    (((tid >> 6) & 1)) * 2048 + (tid & 63) * 16;
  const int dT = tid * 16;

  i32x16 acc[4][2] = {};
  const i32x16 Z16 = {};

  auto stAqh = [&](int kc2, int b2) {
    const int kA = kc2 * 64;
    gl16(aqh0 + kA, lds + b2 + dT);
    gl16(aqh0 + 131072 + kA, lds + b2 + 8192 + dT);
  };
  auto stAql = [&](int kc2, int b2) {
    const int kA = kc2 * 64;
    gl16(aql0 + kA, lds + b2 + 16384 + dT);
    gl16(aql0 + 131072 + kA, lds + b2 + 24576 + dT);
  };
  auto stBph = [&](int kc2, int b2) {
    const char* p = wb0 + kc2 * 4096;
    gl16(p, lds + b2 + 32768 + dT);
    gl16(p + 262144, lds + b2 + 40960 + dT);
  };
  auto stBpl = [&](int kc2, int b2) {
    const char* p = wb0 + kc2 * 4096 + 1024;
    gl16(p, lds + b2 + 49152 + dT);
    gl16(p + 262144, lds + b2 + 57344 + dT);
  };

  // prologue: chunk 0 (order: Aqh, Bpl, Bph, Aql); publish Aqh+Bpl
  stAqh(0, 0); stBpl(0, 0); stBph(0, 0); stAql(0, 0);
  VMC(4);
  BAR;

  auto chunk = [&](int kc, bool last) {
    const int bo = (kc & 1) * 65536, nbuf = bo ^ 65536;
    i32x4 aH[4][2], aL[4][2], bH[2][2], bL[2][2];

    // ---- P1: stage next Aqh+Bpl; publish this chunk's Aqh+Bpl; alpha pass
    if (!last) { stAqh(kc + 1, nbuf); stBpl(kc + 1, nbuf); VMC(8); }
    else       { VMC(4); }
    BAR; SGB;
#pragma unroll
    for (int mt = 0; mt < 4; ++mt)
#pragma unroll
      for (int ks = 0; ks < 2; ++ks)
        aH[mt][ks] = *(const i32x4*)(lds + bo + ((wr * 4 + mt) * 2 + ks) * 1024
                                     + l * 16);
#pragma unroll
    for (int nt = 0; nt < 2; ++nt)
#pragma unroll
      for (int ks = 0; ks < 2; ++ks)
        bL[nt][ks] = *(const i32x4*)(lds + bo + 49152 +
                                     ((wc * 2 + nt) * 2 + ks) * 1024 + l * 16);
    __builtin_amdgcn_s_setprio(1);
#pragma unroll
    for (int mt = 0; mt < 4; ++mt)
#pragma unroll
      for (int nt = 0; nt < 2; ++nt) {
        acc[mt][nt] = MFMA32(aH[mt][0], bL[nt][0], acc[mt][nt], 0, 0, 0);
        acc[mt][nt] = MFMA32(aH[mt][1], bL[nt][1], acc[mt][nt], 0, 0, 0);
      }
    __builtin_amdgcn_s_setprio(0);

    // ---- P2: stage next Bph+Aql; publish this chunk's Bph+Aql; beta + fold
    if (!last) { stBph(kc + 1, nbuf); stAql(kc + 1, nbuf); VMC(8); }
    else       { VMC(0); }
    BAR; SGB;
#pragma unroll
    for (int nt = 0; nt < 2; ++nt)
#pragma unroll
      for (int ks = 0; ks < 2; ++ks)
        bH[nt][ks] = *(const i32x4*)(lds + bo + 32768 +
                                     ((wc * 2 + nt) * 2 + ks) * 1024 + l * 16);
    __builtin_amdgcn_s_setprio(1);
#pragma unroll
    for (int mt = 0; mt < 4; ++mt)
#pragma unroll
      for (int nt = 0; nt < 2; ++nt) {
        i32x16 t = MFMA32(aH[mt][0], bH[nt][0], Z16, 0, 0, 0);
        t = MFMA32(aH[mt][1], bH[nt][1], t, 0, 0, 0);
        acc[mt][nt] = acc[mt][nt] + (t << 7);
      }
    __builtin_amdgcn_s_setprio(0);

    // ---- P3: read Aql; WAR barrier; gamma pass
#pragma unroll
    for (int mt = 0; mt < 4; ++mt)
#pragma unroll
      for (int ks = 0; ks < 2; ++ks)
        aL[mt][ks] = *(const i32x4*)(lds + bo + 16384 +
                                     ((wr * 4 + mt) * 2 + ks) * 1024 + l * 16);
    BAR; SGB;
    __builtin_amdgcn_s_setprio(1);
#pragma unroll
    for (int mt = 0; mt < 4; ++mt)
#pragma unroll
      for (int nt = 0; nt < 2; ++nt) {
        acc[mt][nt] = MFMA32(aL[mt][0], bH[nt][0], acc[mt][nt], 0, 0, 0);
        acc[mt][nt] = MFMA32(aL[mt][1], bH[nt][1], acc[mt][nt], 0, 0, 0);
      }
    __builtin_amdgcn_s_setprio(0);
  };

  for (int kc = 0; kc < 15; ++kc) chunk(kc, false);
  chunk(15, true);

  // epilogue: Out = 128*SC*acc + bias
  // C/D 32x32: col = lane&31, row = (r&3) + 8*(r>>2) + 4*(lane>>5)
  const float SCC = 128.0f * (6.0f / 16256.0f) * (0.03125f / 16320.0f);
  const float* bias = (proj == 0) ? bk : (proj == 1 ? bq : bv);
  float* Out = (proj == 0) ? K : (proj == 1 ? Q : V);
  const int rbase = ((l >> 5) << 2);
#pragma unroll
  for (int mt = 0; mt < 4; ++mt) {
#pragma unroll
    for (int nt = 0; nt < 2; ++nt) {
      const int col = wn0 + wc * 64 + nt * 32 + (l & 31);
      const float bb = bias[col];
#pragma unroll
      for (int r = 0; r < 16; ++r) {
        const int row = gm0 + wr * 128 + mt * 32 + (r & 3) + ((r >> 2) << 3)
                        + rbase;
        Out[(size_t)row * 512 + col] = SCC * (float)acc[mt][nt][r] + bb;
      }
    }
  }
}

// ---------------------------------------------------------------------------
// logits: AW[b,t,s] = (1/sqrt(512)) * sum_c K[b*64+t,c] * Q[b*64+s,c]
// ---------------------------------------------------------------------------
__global__ __launch_bounds__(256) void logits_kernel(
    const float* __restrict__ K, const float* __restrict__ Q,
    float* __restrict__ AW) {
  __shared__ float Ks[64][68];
  __shared__ float Qs[64][68];
  const int b = blockIdx.x;
  const float* Kb = K + (size_t)b * 32768;
  const float* Qb = Q + (size_t)b * 32768;
  const int tid = threadIdx.x;
  const int tr = tid >> 4, tc = tid & 15;

  float acc[4][4] = {};
  for (int c0 = 0; c0 < 512; c0 += 64) {
    __syncthreads();
#pragma unroll
    for (int i = 0; i < 4; ++i) {
      int idx = tid + i * 256;
      int row = idx >> 4;
      int c4 = (idx & 15) * 4;
      float4 kv = *(const float4*)&Kb[row * 512 + c0 + c4];
      float4 qv = *(const float4*)&Qb[row * 512 + c0 + c4];
      Ks[c4 + 0][row] = kv.x; Ks[c4 + 1][row] = kv.y;
      Ks[c4 + 2][row] = kv.z; Ks[c4 + 3][row] = kv.w;
      Qs[c4 + 0][row] = qv.x; Qs[c4 + 1][row] = qv.y;
      Qs[c4 + 2][row] = qv.z; Qs[c4 + 3][row] = qv.w;
    }
    __syncthreads();
#pragma unroll 4
    for (int cc = 0; cc < 64; ++cc) {
      float4 kx = *(const float4*)&Ks[cc][tr * 4];
      float4 qx = *(const float4*)&Qs[cc][tc * 4];
#pragma unroll
      for (int i = 0; i < 4; ++i)
#pragma unroll
        for (int j = 0; j < 4; ++j) acc[i][j] += kx[i] * qx[j];
    }
  }
  const float scale = 0.04419417382415922f;
#pragma unroll
  for (int i = 0; i < 4; ++i)
#pragma unroll
    for (int j = 0; j < 4; ++j)
      AW[(size_t)b * 4096 + (tr * 4 + i) * 64 + (tc * 4 + j)] =
          acc[i][j] * scale;
}

// ---------------------------------------------------------------------------
// stats over batch axis: for each (t,s), m = max_b, inv = 1/sum_b exp(l-m).
// ---------------------------------------------------------------------------
__global__ __launch_bounds__(1024) void stats_kernel(
    const float* __restrict__ AW, float* __restrict__ M,
    float* __restrict__ I) {
  __shared__ float red[16][64];
  const int tt = blockIdx.x;
  const int tid = threadIdx.x;
  const int s = tid & 63, bq = tid >> 6;
  const size_t base = (size_t)tt * 64 + s;

  float m = -3.4e38f;
  for (int b = bq * 32; b < bq * 32 + 32; ++b)
    m = fmaxf(m, AW[(size_t)b * 4096 + base]);
  red[bq][s] = m;
  __syncthreads();
#pragma unroll
  for (int i = 0; i < 16; ++i) m = fmaxf(m, red[i][s]);
  __syncthreads();

  float sum = 0.f;
  for (int b = bq * 32; b < bq * 32 + 32; ++b)
    sum += __expf(AW[(size_t)b * 4096 + base] - m);
  red[bq][s] = sum;
  __syncthreads();
  if (bq == 0) {
    sum = 0.f;
#pragma unroll
    for (int i = 0; i < 16; ++i) sum += red[i][s];
    M[tt * 64 + s] = m;
    I[tt * 64 + s] = 1.0f / sum;
  }
}

// ---------------------------------------------------------------------------
// out[b,c,s] = sum_t V[b*64+t, c] * p,  p = exp(AW[b,t,s]-M[t,s])*I[t,s]
// ---------------------------------------------------------------------------
__global__ __launch_bounds__(512) void out_kernel(
    const float* __restrict__ V, const float* __restrict__ AW,
    const float* __restrict__ M, const float* __restrict__ I,
    float* __restrict__ out) {
  __shared__ float Vs[32768];    // [t][c] flat, 128KB
  __shared__ float Ps[64][65];   // 16.25KB
  const int b = blockIdx.x;
  const int tid = threadIdx.x;
  const float* Vb = V + (size_t)b * 32768;
  const float* Pb = AW + (size_t)b * 4096;

#pragma unroll
  for (int j = 0; j < 16; ++j) {
    int u = j * 512 + tid;
    ((float4*)Vs)[u] = ((const float4*)Vb)[u];
  }
  for (int i = tid; i < 4096; i += 512)
    Ps[i >> 6][i & 63] = __expf(Pb[i] - M[i]) * I[i];
  __syncthreads();

  const int s = tid & 63, cw = tid >> 6;  // cw 0..7
  const int c0 = cw * 64;
  float a[64] = {};
  for (int t = 0; t < 64; ++t) {
    float p = Ps[t][s];
    const float4* vr = (const float4*)(Vs + t * 512 + c0);
#pragma unroll
    for (int j = 0; j < 16; ++j) {
      float4 v = vr[j];
      a[4 * j + 0] += v.x * p;
      a[4 * j + 1] += v.y * p;
      a[4 * j + 2] += v.z * p;
      a[4 * j + 3] += v.w * p;
    }
  }
  float* Ob = out + (size_t)b * 32768;
#pragma unroll
  for (int j = 0; j < 64; ++j)
    Ob[(size_t)(c0 + j) * 64 + s] = a[j];
}

// ---------------------------------------------------------------------------
extern "C" void kernel_launch(void* const* d_in, const int* in_sizes, int n_in,
                              void* d_out, int out_size, void* d_ws,
                              size_t ws_size, hipStream_t stream) {
  const float* x  = (const float*)d_in[0];
  const float* Wk = (const float*)d_in[1];
  const float* bk = (const float*)d_in[2];
  const float* Wq = (const float*)d_in[3];
  const float* bq = (const float*)d_in[4];
  const float* Wv = (const float*)d_in[5];
  const float* bv = (const float*)d_in[6];
  float* out = (float*)d_out;

  char* ws = (char*)d_ws;
  unsigned int* XQH = (unsigned int*)(ws + OFF_XQH);
  unsigned int* XQL = (unsigned int*)(ws + OFF_XQL);
  char* WT = ws + OFF_WT;
  float* K  = (float*)(ws + OFF_K);
  float* Q  = (float*)(ws + OFF_Q);
  float* V  = (float*)(ws + OFF_V);
  float* AW = (float*)(ws + OFF_AW);
  float* M  = (float*)(ws + OFF_MS);
  float* I  = (float*)(ws + OFF_MS + 16384);

  const float invXS = 16256.0f / 6.0f;
  const float invWS = 16320.0f / 0.03125f;

  quant_kernel<<<2048, 256, 0, stream>>>(x, XQH, XQL, 8388608, invXS);
  quant_w_kernel<<<1536, 256, 0, stream>>>(Wk, Wq, Wv, WT, invWS);

  gemm_i8<<<768, 512, 0, stream>>>((const char*)XQH, (const char*)XQL,
                                   WT, bk, bq, bv, K, Q, V);

  logits_kernel<<<BATCH, 256, 0, stream>>>(K, Q, AW);
  stats_kernel<<<NT, 1024, 0, stream>>>(AW, M, I);
  out_kernel<<<BATCH, 512, 0, stream>>>(V, AW, M, I, out);
}